// Round 6
// baseline (587.838 us; speedup 1.0000x reference)
//
#include <hip/hip_runtime.h>
#include <stdint.h>

typedef int v4i  __attribute__((ext_vector_type(4)));
typedef int v16i __attribute__((ext_vector_type(16)));

// ---------------------------------------------------------------------------
// async global->LDS, 16 bytes per lane. LDS dest is wave-uniform base +
// lane*16 (HW takes readfirstlane of the provided pointer), so each thread
// passes its own &lds[t*16] and lane 0 of each wave carries the wave base.
// ---------------------------------------------------------------------------
__device__ __forceinline__ void async_load16(const void* g, void* l) {
    auto gp = (const __attribute__((address_space(1))) unsigned int*)(uintptr_t)g;
    auto lp = (__attribute__((address_space(3))) unsigned int*)(unsigned int)(uintptr_t)l;
    __builtin_amdgcn_global_load_lds(gp, lp, 16, 0, 0);
}

// ---------------------------------------------------------------------------
// ws scalar slots: [0..1] uint absmax bits (x, w); floats at byte 8:
// sc[0]=s_x, sc[1]=s_w, sc[2]=1/(s_x*s_w)
// ---------------------------------------------------------------------------
__global__ void k_init(unsigned* bits) {
    if (threadIdx.x < 2) bits[threadIdx.x] = 0u;
}

// Fused absmax over both tensors: blocks [0,XB) scan x, [XB,grid) scan w.
__global__ void k_absmax2(const float4* __restrict__ x, int nx4,
                          const float4* __restrict__ w, int nw4,
                          unsigned* __restrict__ bits) {
    const int XB = 2048;
    const float4* in; int n4, b, nb; unsigned* ob;
    if (blockIdx.x < XB) { in = x; n4 = nx4; b = blockIdx.x;      nb = XB;              ob = bits;     }
    else                 { in = w; n4 = nw4; b = blockIdx.x - XB; nb = gridDim.x - XB;  ob = bits + 1; }
    float m = 0.0f;
    int stride = nb * blockDim.x;
    for (int i = b * blockDim.x + threadIdx.x; i < n4; i += stride) {
        float4 v = in[i];
        m = fmaxf(m, fmaxf(fmaxf(fabsf(v.x), fabsf(v.y)),
                           fmaxf(fabsf(v.z), fabsf(v.w))));
    }
    #pragma unroll
    for (int off = 32; off > 0; off >>= 1)
        m = fmaxf(m, __shfl_down(m, off, 64));
    __shared__ float red[4];
    int lane = threadIdx.x & 63, wv = threadIdx.x >> 6;
    if (lane == 0) red[wv] = m;
    __syncthreads();
    if (threadIdx.x == 0) {
        m = fmaxf(fmaxf(red[0], red[1]), fmaxf(red[2], red[3]));
        // |x| >= 0: IEEE bit pattern of non-negative floats is order-preserving
        atomicMax(ob, __float_as_uint(m));
    }
}

__global__ void k_scales(const unsigned* __restrict__ bits, float* __restrict__ sc) {
    float s[2];
    for (int i = 0; i < 2; ++i) {
        float m = __uint_as_float(bits[i]);
        int ex = 0;
        if (m > 0.0f) {
            int e;
            float f = frexpf(m, &e);      // m = f * 2^e, f in [0.5, 1)
            ex = (f == 0.5f) ? (e - 1) : e;  // exact ceil(log2(m))
        }
        s[i] = ldexpf(1.0f, 7 - ex);       // 2^(8 - ex - 1)
    }
    sc[0] = s[0];
    sc[1] = s[1];
    sc[2] = 1.0f / (s[0] * s[1]);          // powers of two: exact
}

// Fused quant of both tensors. round-half-even (rintf) == jnp.round;
// clip AFTER round, matching reference.
__global__ void k_quant2(const float4* __restrict__ x, int* __restrict__ qx, int nx4,
                         const float4* __restrict__ w, int* __restrict__ qw, int nw4,
                         const float* __restrict__ scp) {
    const int XB = 4096;
    const float4* in; int* out; int n4, b, nb; float s;
    if (blockIdx.x < XB) { in = x; out = qx; n4 = nx4; b = blockIdx.x;      nb = XB;             s = scp[0]; }
    else                 { in = w; out = qw; n4 = nw4; b = blockIdx.x - XB; nb = gridDim.x - XB; s = scp[1]; }
    int stride = nb * blockDim.x;
    for (int i = b * blockDim.x + threadIdx.x; i < n4; i += stride) {
        float4 v = in[i];
        int qa = (int)rintf(v.x * s); qa = qa > 127 ? 127 : (qa < -127 ? -127 : qa);
        int qb = (int)rintf(v.y * s); qb = qb > 127 ? 127 : (qb < -127 ? -127 : qb);
        int qc = (int)rintf(v.z * s); qc = qc > 127 ? 127 : (qc < -127 ? -127 : qc);
        int qd = (int)rintf(v.w * s); qd = qd > 127 ? 127 : (qd < -127 ? -127 : qd);
        out[i] = (qa & 0xff) | ((qb & 0xff) << 8) | ((qc & 0xff) << 16) | (qd << 24);
    }
}

// ---------------------------------------------------------------------------
// int8 NT GEMM, T3+T4 counted-vmcnt schedule (m201-style, adapted to i8).
// C[m][n] = sum_k A[m][k]*B[n][k], both K-major.
// 256x256 tile, BK=64, 512 threads = 8 waves (2m x 4n), per-wave 128x64 out
// = acc[4][2] of v_mfma_i32_32x32x32_i8. 2-deep tile prefetch, raw s_barrier,
// steady-state s_waitcnt vmcnt(4) (one tile = 4 loads/thread stays in
// flight) -- NEVER vmcnt(0) in the main loop (T4; m218: counted-vs-drain0
// = +38..73%).
// LDS: 2 buf x (A 256x64 + B 256x64) = 64 KiB.
// T2 swizzle for 64B rows: physical 16B slot q of row p holds logical
// q ^ ((p>>1)&3) (involution). Read key is per-lane constant (l31>>1)&3
// since all row bases are multiples of 32 -> 4 hits/bank per 32-lane
// phase = b128 floor. Staging writes linearly (global_load_lds), so the
// swizzle is applied on the GLOBAL source chunk (rule #21: both sides).
// Fragment layouts (harness-verified at 586us, unchanged):
//   A: lane holds A[m = lane&31][k = ks*32 + (lane>>5)*16 + j], j=0..15
//   B: lane holds B[n = lane&31][same k slice]
//   C/D: col = lane&31, row = (reg&3) + 8*(reg>>2) + 4*(lane>>5)
// Hazard audit: wait-own-vmcnt(4) -> s_barrier => ALL waves' tile-t loads
// landed before any ds_read; MFMA operands force lgkmcnt before barrier2;
// restage of buf[cur] only after barrier2 (all reads done); per-thread
// load issue order is oldest-tile-first so vmcnt(4) isolates tile t.
// ---------------------------------------------------------------------------
#define GBAR()  __builtin_amdgcn_s_barrier()
#define WAITV4() asm volatile("s_waitcnt vmcnt(4)" ::: "memory")
#define WAITV0() asm volatile("s_waitcnt vmcnt(0)" ::: "memory")

__global__ __launch_bounds__(512, 2) void k_gemm(const signed char* __restrict__ A,
                                                 const signed char* __restrict__ B,
                                                 float* __restrict__ out,
                                                 const float* __restrict__ scp) {
    __shared__ __align__(16) signed char lds[4 * 16384];  // [buf][A|B] 64 KiB
    const int tid  = threadIdx.x;
    const int lane = tid & 63;
    const int wave = tid >> 6;
    const int wm   = wave >> 2;         // 0..1
    const int wn   = wave & 3;          // 0..3
    const int l31  = lane & 31;
    const int lhi  = lane >> 5;

    // T1: XCD-bijective swizzle, nwg=1024 (%8==0). XCD j gets virtual range
    // [j*128,(j+1)*128): n fast (4), m slow -> B (1MB) L2-resident, each
    // A-panel reused 4x within one XCD's L2.
    const int orig = blockIdx.x;
    const int v    = (orig & 7) * 128 + (orig >> 3);
    const int n0   = (v & 3) * 256;
    const int m0   = (v >> 2) * 256;

    v16i acc[4][2];
    #pragma unroll
    for (int a = 0; a < 4; ++a)
        #pragma unroll
        for (int b = 0; b < 2; ++b)
            #pragma unroll
            for (int i = 0; i < 16; ++i) acc[a][b][i] = 0;

    // Staging map: per matrix per tile = 256 rows x 4 slots = 1024 chunks;
    // 512 threads x 2 shots. Shot s, thread t -> chunk i = s*512+t:
    // physical row p = i>>2, slot q = i&3; source slot = q ^ ((p>>1)&3).
    const signed char* gA[2];
    const signed char* gB[2];
    #pragma unroll
    for (int s = 0; s < 2; ++s) {
        int i = s * 512 + tid;
        int p = i >> 2;
        int q = (i & 3) ^ ((p >> 1) & 3);
        gA[s] = A + (size_t)(m0 + p) * 1024 + q * 16;
        gB[s] = B + (size_t)(n0 + p) * 1024 + q * 16;
    }

    // STAGE(cur, k0): 4 gload_lds per thread (A s0, B s0, A s1, B s1).
    auto STAGE = [&](int cur, int k0) {
        signed char* base = lds + cur * 32768;
        #pragma unroll
        for (int s = 0; s < 2; ++s) {
            async_load16(gA[s] + k0, base +         s * 8192 + tid * 16);
            async_load16(gB[s] + k0, base + 16384 + s * 8192 + tid * 16);
        }
    };

    const int key = (l31 >> 1) & 3;     // per-lane constant swizzle key
    auto COMPUTE = [&](int cur) {
        const signed char* Ab = lds + cur * 32768;
        const signed char* Bb = Ab + 16384;
        #pragma unroll
        for (int ks = 0; ks < 2; ++ks) {
            const int slot = ((ks * 2 + lhi) ^ key) * 16;
            v4i af[4], bf[2];
            #pragma unroll
            for (int tm = 0; tm < 4; ++tm)
                af[tm] = *(const v4i*)(Ab + (wm * 128 + tm * 32 + l31) * 64 + slot);
            #pragma unroll
            for (int tn = 0; tn < 2; ++tn)
                bf[tn] = *(const v4i*)(Bb + (wn * 64 + tn * 32 + l31) * 64 + slot);
            #pragma unroll
            for (int tm = 0; tm < 4; ++tm)
                #pragma unroll
                for (int tn = 0; tn < 2; ++tn)
                    acc[tm][tn] = __builtin_amdgcn_mfma_i32_32x32x32_i8(
                        af[tm], bf[tn], acc[tm][tn], 0, 0, 0);
        }
    };

    // prologue: 2 tiles in flight (8 loads/thread outstanding)
    STAGE(0, 0);
    STAGE(1, 64);

    #pragma unroll 2
    for (int t = 0; t < 14; ++t) {
        WAITV4();                       // tile t landed (t+1 still flying)
        GBAR();
        COMPUTE(t & 1);
        GBAR();                         // all waves done reading buf[t&1]
        STAGE(t & 1, (t + 2) * 64);     // refill; outstanding back to 8
    }
    // t = 14: tile 15 still in flight
    WAITV4(); GBAR(); COMPUTE(0); GBAR();
    // t = 15: last tile, drain fully
    WAITV0(); GBAR(); COMPUTE(1);

    const float inv = scp[0];
    #pragma unroll
    for (int tm = 0; tm < 4; ++tm)
        #pragma unroll
        for (int tn = 0; tn < 2; ++tn)
            #pragma unroll
            for (int r = 0; r < 16; ++r) {
                int row = m0 + wm * 128 + tm * 32 + (r & 3) + 8 * (r >> 2) + 4 * lhi;
                int col = n0 + wn * 64 + tn * 32 + l31;
                out[(size_t)row * 1024 + col] = (float)acc[tm][tn][r] * inv;
            }
}

// ---------------------------------------------------------------------------
extern "C" void kernel_launch(void* const* d_in, const int* in_sizes, int n_in,
                              void* d_out, int out_size, void* d_ws, size_t ws_size,
                              hipStream_t stream) {
    const float* x = (const float*)d_in[0];   // [65536,1024]
    const float* w = (const float*)d_in[1];   // [1024,1024]
    // d_in[2] (bias) is unused by the reference
    float* out = (float*)d_out;               // [65536,1024] fp32

    const int NX = 65536 * 1024;              // x elements
    const int NW = 1024 * 1024;               // w elements

    char* ws = (char*)d_ws;
    unsigned* bits = (unsigned*)ws;           // 2 uints
    float* sc = (float*)(ws + 8);             // 3 floats
    signed char* qx = (signed char*)(ws + 256);
    signed char* qw = qx + (size_t)NX;        // + 64 MB

    k_init<<<1, 64, 0, stream>>>(bits);
    // fused absmax: 2048 x-blocks + 128 w-blocks
    k_absmax2<<<2048 + 128, 256, 0, stream>>>((const float4*)x, NX / 4,
                                              (const float4*)w, NW / 4, bits);
    k_scales<<<1, 1, 0, stream>>>(bits, sc);
    // fused quant: 4096 x-blocks + 128 w-blocks
    k_quant2<<<4096 + 128, 256, 0, stream>>>((const float4*)x, (int*)qx, NX / 4,
                                             (const float4*)w, (int*)qw, NW / 4, sc);

    // 256x256 tiles: grid = (1024/256 n) x (65536/256 m) = 1024 blocks
    k_gemm<<<dim3(1024), 512, 0, stream>>>(qx, qw, out, sc + 2);
}

// Round 7
// 574.392 us; speedup vs baseline: 1.0234x; 1.0234x over previous
//
#include <hip/hip_runtime.h>
#include <stdint.h>

typedef int v4i  __attribute__((ext_vector_type(4)));
typedef int v16i __attribute__((ext_vector_type(16)));

// ---------------------------------------------------------------------------
// async global->LDS, 16 bytes per lane. LDS dest is wave-uniform base +
// lane*16 (HW takes readfirstlane of the provided pointer), so each thread
// passes its own &lds[t*16] and lane 0 of each wave carries the wave base.
// ---------------------------------------------------------------------------
__device__ __forceinline__ void async_load16(const void* g, void* l) {
    auto gp = (const __attribute__((address_space(1))) unsigned int*)(uintptr_t)g;
    auto lp = (__attribute__((address_space(3))) unsigned int*)(unsigned int)(uintptr_t)l;
    __builtin_amdgcn_global_load_lds(gp, lp, 16, 0, 0);
}

// ---------------------------------------------------------------------------
// ws scalar slots: [0..1] uint absmax bits (x, w); floats at byte 8:
// sc[0]=s_x, sc[1]=s_w, sc[2]=1/(s_x*s_w)
// ---------------------------------------------------------------------------
__global__ void k_init(unsigned* bits) {
    if (threadIdx.x < 2) bits[threadIdx.x] = 0u;
}

// Fused absmax over both tensors: blocks [0,XB) scan x, [XB,grid) scan w.
__global__ void k_absmax2(const float4* __restrict__ x, int nx4,
                          const float4* __restrict__ w, int nw4,
                          unsigned* __restrict__ bits) {
    const int XB = 2048;
    const float4* in; int n4, b, nb; unsigned* ob;
    if (blockIdx.x < XB) { in = x; n4 = nx4; b = blockIdx.x;      nb = XB;              ob = bits;     }
    else                 { in = w; n4 = nw4; b = blockIdx.x - XB; nb = gridDim.x - XB;  ob = bits + 1; }
    float m = 0.0f;
    int stride = nb * blockDim.x;
    for (int i = b * blockDim.x + threadIdx.x; i < n4; i += stride) {
        float4 v = in[i];
        m = fmaxf(m, fmaxf(fmaxf(fabsf(v.x), fabsf(v.y)),
                           fmaxf(fabsf(v.z), fabsf(v.w))));
    }
    #pragma unroll
    for (int off = 32; off > 0; off >>= 1)
        m = fmaxf(m, __shfl_down(m, off, 64));
    __shared__ float red[4];
    int lane = threadIdx.x & 63, wv = threadIdx.x >> 6;
    if (lane == 0) red[wv] = m;
    __syncthreads();
    if (threadIdx.x == 0) {
        m = fmaxf(fmaxf(red[0], red[1]), fmaxf(red[2], red[3]));
        // |x| >= 0: IEEE bit pattern of non-negative floats is order-preserving
        atomicMax(ob, __float_as_uint(m));
    }
}

__global__ void k_scales(const unsigned* __restrict__ bits, float* __restrict__ sc) {
    float s[2];
    for (int i = 0; i < 2; ++i) {
        float m = __uint_as_float(bits[i]);
        int ex = 0;
        if (m > 0.0f) {
            int e;
            float f = frexpf(m, &e);      // m = f * 2^e, f in [0.5, 1)
            ex = (f == 0.5f) ? (e - 1) : e;  // exact ceil(log2(m))
        }
        s[i] = ldexpf(1.0f, 7 - ex);       // 2^(8 - ex - 1)
    }
    sc[0] = s[0];
    sc[1] = s[1];
    sc[2] = 1.0f / (s[0] * s[1]);          // powers of two: exact
}

// Fused quant of both tensors. round-half-even (rintf) == jnp.round;
// clip AFTER round, matching reference.
__global__ void k_quant2(const float4* __restrict__ x, int* __restrict__ qx, int nx4,
                         const float4* __restrict__ w, int* __restrict__ qw, int nw4,
                         const float* __restrict__ scp) {
    const int XB = 4096;
    const float4* in; int* out; int n4, b, nb; float s;
    if (blockIdx.x < XB) { in = x; out = qx; n4 = nx4; b = blockIdx.x;      nb = XB;             s = scp[0]; }
    else                 { in = w; out = qw; n4 = nw4; b = blockIdx.x - XB; nb = gridDim.x - XB; s = scp[1]; }
    int stride = nb * blockDim.x;
    for (int i = b * blockDim.x + threadIdx.x; i < n4; i += stride) {
        float4 v = in[i];
        int qa = (int)rintf(v.x * s); qa = qa > 127 ? 127 : (qa < -127 ? -127 : qa);
        int qb = (int)rintf(v.y * s); qb = qb > 127 ? 127 : (qb < -127 ? -127 : qb);
        int qc = (int)rintf(v.z * s); qc = qc > 127 ? 127 : (qc < -127 ? -127 : qc);
        int qd = (int)rintf(v.w * s); qd = qd > 127 ? 127 : (qd < -127 ? -127 : qd);
        out[i] = (qa & 0xff) | ((qb & 0xff) << 8) | ((qc & 0xff) << 16) | (qd << 24);
    }
}

// ---------------------------------------------------------------------------
// int8 NT GEMM, TRUE fine-interleaved counted-vmcnt schedule (T3+T4+T5).
// C[m][n] = sum_k A[m][k]*B[n][k], both K-major.
// 256x256 tile, BK=64, 16 K-tiles, 512 threads = 8 waves (2m x 4n),
// per-wave 128x64 out = acc[4][2] of v_mfma_i32_32x32x32_i8.
//
// KEY CHANGE vs the (neutral) round-6 kernel: 3 LDS buffers (96 KiB,
// 1 block/CU) so tile t+2's staging is issued INSIDE tile t's compute
// phases -- 2 buffers force end-of-tile staging, which degenerates to a
// 2-phase schedule (regime gate: T4 is null there, m196/m248v2).
// Per K-tile: ONE barrier (wait-own-vmcnt -> s_barrier -> fence), then
// 4 phases of {ds_read_b128 x2-4 -> issue 1 global_load_lds piece ->
// setprio(1) -> 4 MFMA -> setprio(0)}. Steady state vmcnt(4): tile t+1's
// 4 loads stay in flight across the barrier; drain only at final tile.
//
// Race audit (m152 discipline): stage targets buf last read at t-1; the
// barrier at tile-t entry proves all waves left t-1. Stage issues are
// after that barrier. Per-thread load order is oldest-tile-first
// (prologue t0x4,t1x4, then 4/tile), so vmcnt(4) == "tiles <= t landed".
// A wave's own loads write buf[t+2], disjoint from buf[t]/buf[t+1] reads.
//
// T2 swizzle for 64B rows (harness-verified layout, unchanged from r5/r6):
// physical 16B slot q of row p holds logical q ^ ((p>>1)&3); staging
// applies the involution on the GLOBAL source slot (rule #21), reads
// apply it on the ds_read addr. Read key is per-lane constant (l31>>1)&3
// (row bases are multiples of 32). 4 hits/bank per 32-lane phase = floor.
// Fragment layouts (harness-verified):
//   A: lane holds A[m = lane&31][k = ks*32 + (lane>>5)*16 + j], j=0..15
//   B: lane holds B[n = lane&31][same k slice]
//   C/D: col = lane&31, row = (reg&3) + 8*(reg>>2) + 4*(lane>>5)
// ---------------------------------------------------------------------------
#define GBAR()  __builtin_amdgcn_s_barrier()
#define WAITV4() asm volatile("s_waitcnt vmcnt(4)" ::: "memory")
#define WAITV0() asm volatile("s_waitcnt vmcnt(0)" ::: "memory")
#define CFENCE() asm volatile("" ::: "memory")

__global__ __launch_bounds__(512, 2) void k_gemm(const signed char* __restrict__ A,
                                                 const signed char* __restrict__ B,
                                                 float* __restrict__ out,
                                                 const float* __restrict__ scp) {
    __shared__ __align__(16) signed char lds[3 * 32768];  // 3 x (A 16K + B 16K)
    const int tid  = threadIdx.x;
    const int lane = tid & 63;
    const int wave = tid >> 6;
    const int wm   = wave >> 2;         // 0..1
    const int wn   = wave & 3;          // 0..3
    const int l31  = lane & 31;
    const int lhi  = lane >> 5;

    // T1: XCD-bijective swizzle, nwg=1024 (%8==0). XCD j gets virtual range
    // [j*128,(j+1)*128): n fast (4), m slow -> B (1MB) L2-resident, each
    // A-panel reused 4x within one XCD's L2.
    const int orig = blockIdx.x;
    const int v    = (orig & 7) * 128 + (orig >> 3);
    const int n0   = (v & 3) * 256;
    const int m0   = (v >> 2) * 256;

    v16i acc[4][2];
    #pragma unroll
    for (int a = 0; a < 4; ++a)
        #pragma unroll
        for (int b = 0; b < 2; ++b)
            #pragma unroll
            for (int i = 0; i < 16; ++i) acc[a][b][i] = 0;

    // Staging map: per matrix per tile = 256 rows x 4 slots = 1024 chunks;
    // 512 threads x 2 shots. Shot s, thread t -> chunk i = s*512+t:
    // physical row p = i>>2, slot q = i&3; source slot = q ^ ((p>>1)&3).
    const signed char* gA[2];
    const signed char* gB[2];
    #pragma unroll
    for (int s = 0; s < 2; ++s) {
        int i = s * 512 + tid;
        int p = i >> 2;
        int q = (i & 3) ^ ((p >> 1) & 3);
        gA[s] = A + (size_t)(m0 + p) * 1024 + q * 16;
        gB[s] = B + (size_t)(n0 + p) * 1024 + q * 16;
    }

    // One staging piece: j=0 -> A shot0, j=1 -> B shot0, j=2 -> A shot1,
    // j=3 -> B shot1. 4 pieces = one full K-tile (A and B).
    auto STAGE_PIECE = [&](signed char* base, int k0, int j) {
        int s = j >> 1;
        if ((j & 1) == 0) async_load16(gA[s] + k0, base +         s * 8192 + tid * 16);
        else              async_load16(gB[s] + k0, base + 16384 + s * 8192 + tid * 16);
    };

    // prologue: tiles 0 and 1 fully staged (8 loads/thread in flight)
    {
        signed char* b0 = lds;
        signed char* b1 = lds + 32768;
        #pragma unroll
        for (int j = 0; j < 4; ++j) STAGE_PIECE(b0, 0, j);
        #pragma unroll
        for (int j = 0; j < 4; ++j) STAGE_PIECE(b1, 64, j);
    }

    const int key = (l31 >> 1) & 3;     // per-lane constant swizzle key

    signed char* rd  = lds;             // tile t
    signed char* mid = lds + 32768;     // tile t+1 (landing)
    signed char* st  = lds + 65536;     // tile t+2 (stage target)

    #pragma unroll
    for (int t = 0; t < 16; ++t) {
        if (t == 15) { WAITV0(); } else { WAITV4(); }   // own tile-t loads done
        GBAR();                                          // => ALL waves' done
        CFENCE();                                        // no ds_read hoisting
        const signed char* Ab = rd;
        const signed char* Bb = rd + 16384;
        const int k2 = (t + 2) * 64;
        const bool dostage = (t < 14);
        #pragma unroll
        for (int ks = 0; ks < 2; ++ks) {
            const int slot = ((ks * 2 + lhi) ^ key) * 16;
            v4i bf0 = *(const v4i*)(Bb + (wn * 64 +      l31) * 64 + slot);
            v4i bf1 = *(const v4i*)(Bb + (wn * 64 + 32 + l31) * 64 + slot);
            #pragma unroll
            for (int h = 0; h < 2; ++h) {
                v4i a0 = *(const v4i*)(Ab + (wm * 128 + (h * 2    ) * 32 + l31) * 64 + slot);
                v4i a1 = *(const v4i*)(Ab + (wm * 128 + (h * 2 + 1) * 32 + l31) * 64 + slot);
                if (dostage) STAGE_PIECE(st, k2, ks * 2 + h);   // 1 load/phase
                __builtin_amdgcn_s_setprio(1);
                acc[h*2  ][0] = __builtin_amdgcn_mfma_i32_32x32x32_i8(a0, bf0, acc[h*2  ][0], 0, 0, 0);
                acc[h*2  ][1] = __builtin_amdgcn_mfma_i32_32x32x32_i8(a0, bf1, acc[h*2  ][1], 0, 0, 0);
                acc[h*2+1][0] = __builtin_amdgcn_mfma_i32_32x32x32_i8(a1, bf0, acc[h*2+1][0], 0, 0, 0);
                acc[h*2+1][1] = __builtin_amdgcn_mfma_i32_32x32x32_i8(a1, bf1, acc[h*2+1][1], 0, 0, 0);
                __builtin_amdgcn_s_setprio(0);
            }
        }
        // rotate buffers (constant-folded by full unroll)
        signed char* tmp = rd; rd = mid; mid = st; st = tmp;
    }

    const float inv = scp[0];
    #pragma unroll
    for (int tm = 0; tm < 4; ++tm)
        #pragma unroll
        for (int tn = 0; tn < 2; ++tn)
            #pragma unroll
            for (int r = 0; r < 16; ++r) {
                int row = m0 + wm * 128 + tm * 32 + (r & 3) + 8 * (r >> 2) + 4 * lhi;
                int col = n0 + wn * 64 + tn * 32 + l31;
                out[(size_t)row * 1024 + col] = (float)acc[tm][tn][r] * inv;
            }
}

// ---------------------------------------------------------------------------
extern "C" void kernel_launch(void* const* d_in, const int* in_sizes, int n_in,
                              void* d_out, int out_size, void* d_ws, size_t ws_size,
                              hipStream_t stream) {
    const float* x = (const float*)d_in[0];   // [65536,1024]
    const float* w = (const float*)d_in[1];   // [1024,1024]
    // d_in[2] (bias) is unused by the reference
    float* out = (float*)d_out;               // [65536,1024] fp32

    const int NX = 65536 * 1024;              // x elements
    const int NW = 1024 * 1024;               // w elements

    char* ws = (char*)d_ws;
    unsigned* bits = (unsigned*)ws;           // 2 uints
    float* sc = (float*)(ws + 8);             // 3 floats
    signed char* qx = (signed char*)(ws + 256);
    signed char* qw = qx + (size_t)NX;        // + 64 MB

    k_init<<<1, 64, 0, stream>>>(bits);
    // fused absmax: 2048 x-blocks + 128 w-blocks
    k_absmax2<<<2048 + 128, 256, 0, stream>>>((const float4*)x, NX / 4,
                                              (const float4*)w, NW / 4, bits);
    k_scales<<<1, 1, 0, stream>>>(bits, sc);
    // fused quant: 4096 x-blocks + 128 w-blocks
    k_quant2<<<4096 + 128, 256, 0, stream>>>((const float4*)x, (int*)qx, NX / 4,
                                             (const float4*)w, (int*)qw, NW / 4, sc);

    // 256x256 tiles: grid = (1024/256 n) x (65536/256 m) = 1024 blocks
    k_gemm<<<dim3(1024), 512, 0, stream>>>(qx, qw, out, sc + 2);
}